// Round 1
// baseline (158.803 us; speedup 1.0000x reference)
//
#include <hip/hip_runtime.h>
#include <stdint.h>
#include <math.h>

// Problem constants
#define NB_B 8
#define NB_S 512
#define NB_D 1024
#define NB_H 16
#define NB_HD 64
#define NP 196            // image patches: bidirectional prefix block
#define MTOT 4096         // B*S

// Workspace layout (offsets in bf16/short elements). Total 48 MB.
// ALL matrices that feed async16 staging (or wave-frag loads) are stored
// CHUNK-SWIZZLED: chunk (g = 16-row group, kb = 32-col block) = 512 shorts,
// [lane=quad*16+c][8 shorts], c = row%16, quad = (col%32)/8.
// => async16/frag reads are contiguous 1KB wave bursts (R9-verified win).
#define OFF_XB 0          // x bf16 swizzled:      [g 0..255][kb 0..31][64][8]
#define OFF_WQ 4194304    // w swizzled (each):    [gn 0..63][kb 0..31][64][8]
#define OFF_WK 5242880
#define OFF_WV 6291456
#define OFF_WO 7340032
#define OFF_Q  8388608    // Q swizzled: [bh][qg 0..31][dblk 0..1][64][8]
#define OFF_K  12582912   // K swizzled: [bh][kg 0..31][dblk 0..1][64][8]
#define OFF_VT 16777216   // V^T swizzled: [bh][dg 0..3][kblk 0..15][64][8]
#define OFF_CT 20971520   // ctx swizzled like XB: [g 0..255][kb 0..31][64][8]

typedef __attribute__((ext_vector_type(8))) short bf16x8;
typedef __attribute__((ext_vector_type(4))) float f32x4;
typedef __attribute__((ext_vector_type(4))) short s16x4;
typedef __attribute__((ext_vector_type(8))) short s16x8;

__device__ __forceinline__ short f2bf(float f) {
  union { float f; uint32_t u; } c; c.f = f;
  uint32_t r = (c.u + 0x7fffu + ((c.u >> 16) & 1u)) >> 16;   // RNE
  return (short)r;
}

// pack two fp32 -> one dword of two bf16 (round-half-up; softmax weights >=0)
__device__ __forceinline__ uint32_t pack2bf(float lo, float hi) {
  uint32_t ulo = __float_as_uint(lo) + 0x8000u;
  uint32_t uhi = __float_as_uint(hi) + 0x8000u;
  return __builtin_amdgcn_perm(uhi, ulo, 0x07060302u);  // [bf16(hi)|bf16(lo)]
}

__device__ __forceinline__ void async16(void* lds, const void* g) {
  // global -> LDS direct copy, 16B per lane; LDS dest = uniform base + lane*16
  __builtin_amdgcn_global_load_lds(
      (const __attribute__((address_space(1))) void*)g,
      (__attribute__((address_space(3))) void*)lds, 16, 0, 0);
}

// ---------------------------------------------------------------------------
// cvt5 v3: fp32 -> bf16 + chunk-swizzle via LDS transpose (R10-verified).
// ---------------------------------------------------------------------------
__global__ __launch_bounds__(256) void cvt5(const float* __restrict__ x,
                                            const float* __restrict__ wq,
                                            const float* __restrict__ wk,
                                            const float* __restrict__ wv,
                                            const float* __restrict__ wo,
                                            short* __restrict__ ws) {
  __shared__ uint32_t lt[16 * 513];   // 16 rows x 513 dwords (+pad: phase-2 conflict-free)
  int b = blockIdx.x, t = threadIdx.x;
  const float* src; short* dst; float scale;
  if (b < 256) {
    src = x + b * 16384;            // rows b*16 .. b*16+15
    dst = ws + OFF_XB + b * 16384;
    scale = 1.0f;
  } else {
    int wi = (b - 256) >> 6, gn = (b - 256) & 63;
    switch (wi) {
      case 0:  src = wq + gn * 16384; scale = 0.125f; break;
      case 1:  src = wk + gn * 16384; scale = 1.0f;   break;
      case 2:  src = wv + gn * 16384; scale = 1.0f;   break;
      default: src = wo + gn * 16384; scale = 1.0f;   break;
    }
    dst = ws + OFF_WQ + wi * 1048576 + gn * 16384;
  }
  // --- phase 1: coalesced float4 reads -> packed bf16 pairs in LDS ---
#pragma unroll
  for (int i = 0; i < 16; ++i) {
    int flat = t + i * 256;          // float4 id, 0..4095
    int row = flat >> 8, col4 = flat & 255;
    float4 v = *(const float4*)(src + flat * 4);
    uint32_t lo = (uint32_t)(uint16_t)f2bf(v.x * scale) |
                  ((uint32_t)(uint16_t)f2bf(v.y * scale) << 16);
    uint32_t hi = (uint32_t)(uint16_t)f2bf(v.z * scale) |
                  ((uint32_t)(uint16_t)f2bf(v.w * scale) << 16);
    lt[row * 513 + col4 * 2]     = lo;
    lt[row * 513 + col4 * 2 + 1] = hi;
  }
  __syncthreads();
  // --- phase 2: swizzled LDS gather -> contiguous 16B global writes ---
#pragma unroll
  for (int i = 0; i < 8; ++i) {
    int s = t + i * 256;             // chunk-slot id, 0..2047
    int kb = s >> 6, l = s & 63, quad = l >> 4, cc = l & 15;
    int base = cc * 513 + kb * 16 + quad * 4;
    union { uint32_t u[4]; s16x8 v; } o;
    o.u[0] = lt[base];     o.u[1] = lt[base + 1];
    o.u[2] = lt[base + 2]; o.u[3] = lt[base + 3];
    *(s16x8*)(dst + s * 8) = o.v;
  }
}

// ---------------------------------------------------------------------------
// QKV projection R12: fused (N=3072) 256x256-tile, BK=64, 8-wave, 8-phase
// counted-vmcnt schedule (T3+T4+T5). 192 blocks x 512 threads, 128 KiB LDS
// (double-buffered K-tiles). Per phase: ds-read one quadrant's frags ||
// issue one 16KB half-tile of global_load_lds prefetch -> s_barrier ->
// lgkmcnt(0) -> setprio(1) + 16 MFMA + setprio(0) -> counted vmcnt(4)
// (only at kk-group boundaries; NEVER 0 in the main loop) -> s_barrier.
// Chunk-swizzled layout keeps every ds_read_b128 a conflict-free 1KB burst
// (T2 prerequisite already satisfied). Epilogue identical math to R9-R11,
// extended to the 8x4 per-wave fragment grid.
// ---------------------------------------------------------------------------
__global__ __launch_bounds__(512, 2) void gemm_qkv8(short* __restrict__ ws) {
  // LDS: [buf 0/1][A 32 chunks | B 32 chunks][512 shorts] = 128 KiB
  __shared__ __align__(16) short LDS[65536];
  int bx = blockIdx.x;              // 0..191
  int mt = bx / 12, nt = bx % 12;   // 16 m-tiles x 12 n-tiles (fused QKV)
  int m0 = mt << 8;
  int wsel = nt >> 2;               // 0=Q 1=K 2=V (256 | 1024)
  int nw0 = (nt & 3) << 8;          // within-matrix feature base
  const short* A  = ws + OFF_XB;    // [g 0..255][kb 0..31][64][8]
  const short* Bw = ws + OFF_WQ;    // fused: groups 0..191 (WQ|WK|WV contiguous)
  int t0 = threadIdx.x, lane = t0 & 63, wvi = t0 >> 6;
  int c = lane & 15, quad = lane >> 4;
  int wm = wvi >> 2, wn = wvi & 3;  // 2M x 4N waves; wave tile 128m x 64n
  f32x4 acc[8][4] = {};

  // ---- prologue: stage K-tile 0 into buf0 (order: A-kk0, B-kk0, A-kk1, B-kk1)
  // so vmcnt(4) below == "kk0 halves landed".
#pragma unroll
  for (int kkh = 0; kkh < 2; ++kkh) {
#pragma unroll
    for (int i2 = 0; i2 < 2; ++i2) {
      int g = wvi * 2 + i2;
      async16(&LDS[(g * 2 + kkh) << 9],
              A + (((mt * 16 + g) * 32 + kkh) << 9) + lane * 8);
    }
#pragma unroll
    for (int i2 = 0; i2 < 2; ++i2) {
      int g = wvi * 2 + i2;
      async16(&LDS[32768 + ((g * 2 + kkh) << 9)],
              Bw + (((nt * 16 + g) * 32 + kkh) << 9) + lane * 8);
    }
  }
  asm volatile("s_waitcnt vmcnt(4)" ::: "memory");
  __builtin_amdgcn_s_barrier();

  for (int t = 0; t < 16; ++t) {      // 16 K-tiles of BK=64
    int p = t & 1;
    short* Ab = &LDS[p << 14];
    short* Bb = &LDS[32768 + (p << 14)];
    short* An = &LDS[(p ^ 1) << 14];
    short* Bn = &LDS[32768 + ((p ^ 1) << 14)];
    bool st = (t < 15);
    int kbn = (t + 1) * 2;            // global kb base of tile t+1
    bf16x8 af[8];                     // A-frags persist across the 2 nh phases
#pragma unroll
    for (int kkh = 0; kkh < 2; ++kkh) {
#pragma unroll
      for (int nh = 0; nh < 2; ++nh) {
        bf16x8 bfr[2];
        if (nh == 0) {
#pragma unroll
          for (int i = 0; i < 8; ++i)
            af[i] = *(const bf16x8*)&Ab[(((wm * 8 + i) * 2 + kkh) << 9) + lane * 8];
        }
#pragma unroll
        for (int j2 = 0; j2 < 2; ++j2)
          bfr[j2] = *(const bf16x8*)&Bb[(((wn * 4 + nh * 2 + j2) * 2 + kkh) << 9) + lane * 8];
        // stage one half-tile of K-tile t+1 (2 async16/wave): lands 3-4 phases out
        if (st) {
          if (nh == 0) {
#pragma unroll
            for (int i2 = 0; i2 < 2; ++i2) {
              int g = wvi * 2 + i2;
              async16(&An[(g * 2 + kkh) << 9],
                      A + (((mt * 16 + g) * 32 + kbn + kkh) << 9) + lane * 8);
            }
          } else {
#pragma unroll
            for (int i2 = 0; i2 < 2; ++i2) {
              int g = wvi * 2 + i2;
              async16(&Bn[(g * 2 + kkh) << 9],
                      Bw + (((nt * 16 + g) * 32 + kbn + kkh) << 9) + lane * 8);
            }
          }
        }
        __builtin_amdgcn_s_barrier();
        asm volatile("s_waitcnt lgkmcnt(0)" ::: "memory");
        __builtin_amdgcn_sched_barrier(0);
        __builtin_amdgcn_s_setprio(1);
#pragma unroll
        for (int i = 0; i < 8; ++i)
#pragma unroll
          for (int j2 = 0; j2 < 2; ++j2)
            acc[i][nh * 2 + j2] = __builtin_amdgcn_mfma_f32_16x16x32_bf16(
                af[i], bfr[j2], acc[i][nh * 2 + j2], 0, 0, 0);
        __builtin_amdgcn_s_setprio(0);
        if (nh == 1) {
          // counted wait: the kk-group needed by the NEXT two phases was issued
          // 4 phases ago; the last 4 vmem ops are the 2 halves issued since.
          if (st) asm volatile("s_waitcnt vmcnt(4)" ::: "memory");
          else    asm volatile("s_waitcnt vmcnt(0)" ::: "memory");  // last tile: nothing newer to count
        }
        __builtin_amdgcn_s_barrier();
      }
    }
  }

  // ---- epilogue: identical store math to R9-R11, 8x4 fragment grid ----
#pragma unroll
  for (int i = 0; i < 8; ++i) {
#pragma unroll
    for (int j = 0; j < 4; ++j) {
      int nf = nw0 + wn * 64 + j * 16 + c;        // within-matrix feature
      int h = nf >> 6, d = nf & 63;
      int mq = m0 + wm * 128 + i * 16 + quad * 4; // first of the 4 rows (reg dim)
      int bb = mq >> 9, srow = mq & 511;
      if (wsel < 2) {
        // Q_sw / K_sw: [bh][g][dblk][lane=qk*16+(row%16)][jd]; row%16=quad*4+r
        int dblk = d >> 5, qk = (d >> 3) & 3, jd = d & 7;
        int g = srow >> 4;
        short* outp = ws + (wsel == 0 ? OFF_Q : OFF_K);
        size_t base = (size_t)(bb * 16 + h) * 32768 +
                      (size_t)(((g * 2 + dblk) * 64 + qk * 16 + quad * 4)) * 8 + jd;
#pragma unroll
        for (int r = 0; r < 4; ++r) outp[base + r * 8] = f2bf(acc[i][j][r]);
      } else {
        // V_sw: [bh][dg][kblk][lane=qv*16+(d%16)][jv]; keys srow..srow+3
        int dg = d >> 4, cv = d & 15;
        int kblk = srow >> 5, qv = (srow >> 3) & 3, jv = srow & 7;
        s16x4 o;
#pragma unroll
        for (int r = 0; r < 4; ++r) o[r] = f2bf(acc[i][j][r]);
        *(s16x4*)&ws[OFF_VT + (size_t)(bb * 16 + h) * 32768 +
                     (size_t)((dg * 16 + kblk) * 64 + qv * 16 + cv) * 8 + jv] = o;
      }
    }
  }
}

// ---------------------------------------------------------------------------
// Attention v6 (R11): 128-key chunks — half the barrier/drain count.
// ---------------------------------------------------------------------------
__global__ __launch_bounds__(256, 2) void attn(short* __restrict__ ws) {
  __shared__ __align__(16) short Kb[8192];   // 16 chunks: [kgrel 0..7][dblk 0..1]
  __shared__ __align__(16) short Vb[8192];   // 16 chunks: [dg 0..3][kbrel 0..3]
  int bi = blockIdx.x;              // 0..511
  int bh = bi >> 2, qcr = bi & 3;
  int qc = (qcr + bh + 2 * (bh >> 6)) & 3;   // rotate so CU pairs mix light/heavy
  int t = threadIdx.x, lane = t & 63, wvi = t >> 6;
  int c = lane & 15, quad = lane >> 4;
  const short* Qsw  = ws + OFF_Q  + (size_t)bh * 32768;
  const short* Ksw  = ws + OFF_K  + (size_t)bh * 32768;
  const short* Vsw  = ws + OFF_VT + (size_t)bh * 32768;
  short* ct = ws + OFF_CT;
  int b = bh >> 4, h = bh & 15;

  int qt0 = qc * 128 + wvi * 32;    // two 16-row subtiles per wave
  int qt1 = qt0 + 16;
  int kn0 = (qt0 + 16 > NP) ? (qt0 + 16) : NP;
  int kn1 = (qt1 + 16 > NP) ? (qt1 + 16) : NP;
  int knb = (qc * 128 + 128 > NP) ? (qc * 128 + 128) : NP;
  int NCH = (knb + 127) >> 7;       // 128-key chunks staged by the block

  // Q^T B-frags from Q_sw (contiguous 1KB wave bursts)
  int qg0 = qt0 >> 4, qg1 = qt1 >> 4;
  bf16x8 q00 = *(const bf16x8*)(Qsw + ((qg0 * 2 + 0) * 64 + lane) * 8);
  bf16x8 q01 = *(const bf16x8*)(Qsw + ((qg0 * 2 + 1) * 64 + lane) * 8);
  bf16x8 q10 = *(const bf16x8*)(Qsw + ((qg1 * 2 + 0) * 64 + lane) * 8);
  bf16x8 q11 = *(const bf16x8*)(Qsw + ((qg1 * 2 + 1) * 64 + lane) * 8);

  f32x4 acc0[4] = {}, acc1[4] = {}; // ctx^T accumulators per subtile
  float l0 = 0.0f, l1 = 0.0f;       // in-lane softmax denominators
  int L0 = c + ((quad & 1) << 5);   // transpose source lane
  bool hilo = quad >= 2;

  for (int chn = 0; chn < NCH; ++chn) {
    int k0 = chn << 7;              // chunk covers keys k0 .. k0+127
    // --- stage 16 K-chunks + 16 V-chunks, 8 async16 per wave ---
    {
      int kg0 = k0 >> 4;            // first 16-key group
      int kblk0 = k0 >> 5;          // first 32-key block
#pragma unroll
      for (int i = 0; i < 4; ++i) {
        int ch = wvi * 4 + i;       // 0..15, wave-uniform
        int kgrel = ch >> 1, f = ch & 1;
        async16(&Kb[ch << 9], Ksw + (((kg0 + kgrel) * 2 + f) * 64 + lane) * 8);
        int dg = ch >> 2, kbrel = ch & 3;
        async16(&Vb[ch << 9], Vsw + ((dg * 16 + kblk0 + kbrel) * 64 + lane) * 8);
      }
    }
    __syncthreads();                // drains vmcnt for global_load_lds

#pragma unroll
    for (int hf = 0; hf < 2; ++hf) {
      int kh = k0 + (hf << 6);      // this 64-key half
      // K A-frags [m=key16][k=d] and V^T A-frags [m=d16][k=key32+..]
      bf16x8 ak[4][2], av[4][2];
#pragma unroll
      for (int mb = 0; mb < 4; ++mb)
#pragma unroll
        for (int f = 0; f < 2; ++f) {
          ak[mb][f] = *(const bf16x8*)&Kb[((((hf * 4 + mb) << 1) + f) << 9) + lane * 8];
          av[mb][f] = *(const bf16x8*)&Vb[(((mb << 2) + (hf << 1) + f) << 9) + lane * 8];
        }

#pragma unroll
      for (int s = 0; s < 2; ++s) {
        int qt = s ? qt1 : qt0;
        int kn = s ? kn1 : kn0;
        if (kh >= kn) continue;     // subtile finished for this half
        bf16x8 bq0 = s ? q10 : q00;
        bf16x8 bq1 = s ? q11 : q01;
        f32x4* acc = s ? acc1 : acc0;

        // --- S^T = K . Q^T : 4 m-blocks of 16 keys ---
        float p[4][4];
#pragma unroll
        for (int mb = 0; mb < 4; ++mb) {
          f32x4 st = {};
          st = __builtin_amdgcn_mfma_f32_16x16x32_bf16(ak[mb][0], bq0, st, 0, 0, 0);
          st = __builtin_amdgcn_mfma_f32_16x16x32_bf16(ak[mb][1], bq1, st, 0, 0, 0);
#pragma unroll
          for (int r = 0; r < 4; ++r) p[mb][r] = __expf(st[r]);
        }

        // --- prefix/causal mask (only halves that can contain invalid keys) ---
        if ((kh + 64 > NP) && (kh + 64 > qt + 1)) {
          int row = qt + c;
#pragma unroll
          for (int mb = 0; mb < 4; ++mb)
#pragma unroll
            for (int r = 0; r < 4; ++r) {
              int key = kh + mb * 16 + (quad << 2) + r;
              bool v = (row < NP) ? (key < NP) : (key <= row);
              p[mb][r] = v ? p[mb][r] : 0.0f;
            }
        }
        float ls = 0.0f;
#pragma unroll
        for (int mb = 0; mb < 4; ++mb)
#pragma unroll
          for (int r = 0; r < 4; ++r) ls += p[mb][r];
        if (s) l1 += ls; else l0 += ls;

        // --- per 32-key half: transpose to B-frag (R3-verified), then PV ---
#pragma unroll
        for (int hh = 0; hh < 2; ++hh) {
          float* pa = p[2 * hh];    // keys kh+32hh+{4quad'+r}
          float* pb = p[2 * hh + 1];
          uint32_t e0 = pack2bf(pa[0], pa[1]);
          uint32_t e1 = pack2bf(pa[2], pa[3]);
          uint32_t e2 = pack2bf(pb[0], pb[1]);
          uint32_t e3 = pack2bf(pb[2], pb[3]);
          uint32_t a0 = (uint32_t)__shfl((int)e0, L0);
          uint32_t b0 = (uint32_t)__shfl((int)e1, L0);
          uint32_t a1 = (uint32_t)__shfl((int)e0, L0 + 16);
          uint32_t b1 = (uint32_t)__shfl((int)e1, L0 + 16);
          uint32_t c0 = (uint32_t)__shfl((int)e2, L0);
          uint32_t d0 = (uint32_t)__shfl((int)e3, L0);
          uint32_t c1 = (uint32_t)__shfl((int)e2, L0 + 16);
          uint32_t d1 = (uint32_t)__shfl((int)e3, L0 + 16);
          union { uint32_t u[4]; bf16x8 v; } bp;
          bp.u[0] = hilo ? c0 : a0;
          bp.u[1] = hilo ? d0 : b0;
          bp.u[2] = hilo ? c1 : a1;
          bp.u[3] = hilo ? d1 : b1;
#pragma unroll
          for (int db = 0; db < 4; ++db)
            acc[db] = __builtin_amdgcn_mfma_f32_16x16x32_bf16(av[db][hh], bp.v, acc[db], 0, 0, 0);
        }
      }
    }
    __syncthreads();                // protect LDS before next stage
  }

  // --- finalize: quad-reduce l, normalize, store ctx SWIZZLED (CT_sw) ---
#pragma unroll
  for (int s = 0; s < 2; ++s) {
    float l = s ? l1 : l0;
    f32x4* acc = s ? acc1 : acc0;
    int qt = s ? qt1 : qt0;
    l += __shfl_xor(l, 16);
    l += __shfl_xor(l, 32);
    float inv = 1.0f / l;
    int g = (b * 512 + qt) >> 4;    // 16-row group (qt multiple of 16)
#pragma unroll
    for (int db = 0; db < 4; ++db) {
      int col0 = h * 64 + db * 16 + quad * 4;   // first of 4 cols (r-run)
      int kb = col0 >> 5, qp = (col0 & 31) >> 3, jo = col0 & 7;
      s16x4 o;
#pragma unroll
      for (int r = 0; r < 4; ++r) o[r] = f2bf(acc[db][r] * inv);
      *(s16x4*)&ct[(size_t)((g * 32 + kb) * 64 + qp * 16 + c) * 8 + jo] = o;
    }
  }
}

// ---------------------------------------------------------------------------
// Output projection (R9 structure, unchanged): 64m x 128n, BK=64, 512 blocks,
// swizzled 1KB-burst staging from CT_sw / WO_sw.
// ---------------------------------------------------------------------------
__global__ __launch_bounds__(256, 2) void gemm_out(const short* __restrict__ ws,
                                                   const float* __restrict__ bias,
                                                   float* __restrict__ out) {
  __shared__ __align__(16) short As[4096];   // 8 chunks
  __shared__ __align__(16) short Bs[8192];   // 16 chunks
  int bx = blockIdx.x;              // 0..511
  int mt = bx >> 3, nt = bx & 7;
  int m0 = mt << 6, n0 = nt << 7;
  const short* A  = ws + OFF_CT;
  const short* Bw = ws + OFF_WO;
  int t = threadIdx.x, lane = t & 63, wvi = t >> 6;
  int c = lane & 15, quad = lane >> 4;
  int wm = wvi >> 1, wn = wvi & 1;   // wave tile 32m x 64n
  int g0 = m0 >> 4, gn0 = n0 >> 4;
  f32x4 acc[2][4] = {};

  for (int kk = 0; kk < 1024; kk += 64) {
    int kb = kk >> 5;
#pragma unroll
    for (int i = 0; i < 6; ++i) {
      int ch = wvi * 6 + i;
      if (ch < 8) {
        int mg = ch >> 1, kh = ch & 1;
        async16(&As[ch << 9], A + ((g0 + mg) * 32 + kb + kh) * 512 + lane * 8);
      } else {
        int cb = ch - 8, mg = cb >> 1, kh = cb & 1;
        async16(&Bs[cb << 9], Bw + ((gn0 + mg) * 32 + kb + kh) * 512 + lane * 8);
      }
    }
    __syncthreads();                // drains vmcnt for global_load_lds

    bf16x8 af[2][2], bfr[4][2];
#pragma unroll
    for (int i = 0; i < 2; ++i)
#pragma unroll
      for (int kh = 0; kh < 2; ++kh)
        af[i][kh] = *(const bf16x8*)&As[((((wm * 2 + i) << 1) + kh) << 9) + lane * 8];
#pragma unroll
    for (int j = 0; j < 4; ++j)
#pragma unroll
      for (int kh = 0; kh < 2; ++kh)
        bfr[j][kh] = *(const bf16x8*)&Bs[((((wn * 4 + j) << 1) + kh) << 9) + lane * 8];
#pragma unroll
    for (int kh = 0; kh < 2; ++kh)
#pragma unroll
      for (int i = 0; i < 2; ++i)
#pragma unroll
        for (int j = 0; j < 4; ++j)
          acc[i][j] = __builtin_amdgcn_mfma_f32_16x16x32_bf16(af[i][kh], bfr[j][kh], acc[i][j], 0, 0, 0);
    __syncthreads();                // protect LDS before next stage
  }

#pragma unroll
  for (int j = 0; j < 4; ++j) {
    int n = n0 + wn * 64 + j * 16 + c;
    float bj = bias[n];
#pragma unroll
    for (int i = 0; i < 2; ++i) {
      int mq = m0 + wm * 32 + i * 16 + quad * 4;
#pragma unroll
      for (int r = 0; r < 4; ++r)
        out[(size_t)(mq + r) * 1024 + n] = acc[i][j][r] + bj;
    }
  }
}

extern "C" void kernel_launch(void* const* d_in, const int* in_sizes, int n_in,
                              void* d_out, int out_size, void* d_ws, size_t ws_size,
                              hipStream_t stream) {
  (void)in_sizes; (void)n_in; (void)out_size; (void)ws_size;  // needs 48 MB of d_ws
  const float* x  = (const float*)d_in[0];
  const float* wq = (const float*)d_in[1];
  const float* wk = (const float*)d_in[2];
  const float* wv = (const float*)d_in[3];
  const float* wo = (const float*)d_in[4];
  const float* bo = (const float*)d_in[5];
  short* ws = (short*)d_ws;
  float* out = (float*)d_out;

  cvt5<<<512, 256, 0, stream>>>(x, wq, wk, wv, wo, ws);
  gemm_qkv8<<<192, 512, 0, stream>>>(ws);
  attn<<<512, 256, 0, stream>>>(ws);
  gemm_out<<<512, 256, 0, stream>>>(ws, bo, out);
}

// Round 2
// 155.097 us; speedup vs baseline: 1.0239x; 1.0239x over previous
//
#include <hip/hip_runtime.h>
#include <stdint.h>
#include <math.h>

// Problem constants
#define NB_B 8
#define NB_S 512
#define NB_D 1024
#define NB_H 16
#define NB_HD 64
#define NP 196            // image patches: bidirectional prefix block
#define MTOT 4096         // B*S

// Workspace layout (offsets in bf16/short elements). Total 48 MB.
// ALL matrices that feed async16 staging (or wave-frag loads) are stored
// CHUNK-SWIZZLED: chunk (g = 16-row group, kb = 32-col block) = 512 shorts,
// [lane=quad*16+c][8 shorts], c = row%16, quad = (col%32)/8.
// => async16/frag reads are contiguous 1KB wave bursts (R9-verified win).
#define OFF_XB 0          // x bf16 swizzled:      [g 0..255][kb 0..31][64][8]
#define OFF_WQ 4194304    // w swizzled (each):    [gn 0..63][kb 0..31][64][8]
#define OFF_WK 5242880
#define OFF_WV 6291456
#define OFF_WO 7340032
#define OFF_Q  8388608    // Q swizzled: [bh][qg 0..31][dblk 0..1][64][8]
#define OFF_K  12582912   // K swizzled: [bh][kg 0..31][dblk 0..1][64][8]
#define OFF_VT 16777216   // V^T swizzled: [bh][dg 0..3][kblk 0..15][64][8]
#define OFF_CT 20971520   // ctx swizzled like XB: [g 0..255][kb 0..31][64][8]

typedef __attribute__((ext_vector_type(8))) short bf16x8;
typedef __attribute__((ext_vector_type(4))) float f32x4;
typedef __attribute__((ext_vector_type(4))) short s16x4;
typedef __attribute__((ext_vector_type(8))) short s16x8;

__device__ __forceinline__ short f2bf(float f) {
  union { float f; uint32_t u; } c; c.f = f;
  uint32_t r = (c.u + 0x7fffu + ((c.u >> 16) & 1u)) >> 16;   // RNE
  return (short)r;
}

// pack two fp32 -> one dword of two bf16 (round-half-up; softmax weights >=0)
__device__ __forceinline__ uint32_t pack2bf(float lo, float hi) {
  uint32_t ulo = __float_as_uint(lo) + 0x8000u;
  uint32_t uhi = __float_as_uint(hi) + 0x8000u;
  return __builtin_amdgcn_perm(uhi, ulo, 0x07060302u);  // [bf16(hi)|bf16(lo)]
}

__device__ __forceinline__ void async16(void* lds, const void* g) {
  // global -> LDS direct copy, 16B per lane; LDS dest = uniform base + lane*16
  __builtin_amdgcn_global_load_lds(
      (const __attribute__((address_space(1))) void*)g,
      (__attribute__((address_space(3))) void*)lds, 16, 0, 0);
}

// ---------------------------------------------------------------------------
// cvt5 v3: fp32 -> bf16 + chunk-swizzle via LDS transpose (R10-verified).
// ---------------------------------------------------------------------------
__global__ __launch_bounds__(256) void cvt5(const float* __restrict__ x,
                                            const float* __restrict__ wq,
                                            const float* __restrict__ wk,
                                            const float* __restrict__ wv,
                                            const float* __restrict__ wo,
                                            short* __restrict__ ws) {
  __shared__ uint32_t lt[16 * 513];   // 16 rows x 513 dwords (+pad: phase-2 conflict-free)
  int b = blockIdx.x, t = threadIdx.x;
  const float* src; short* dst; float scale;
  if (b < 256) {
    src = x + b * 16384;            // rows b*16 .. b*16+15
    dst = ws + OFF_XB + b * 16384;
    scale = 1.0f;
  } else {
    int wi = (b - 256) >> 6, gn = (b - 256) & 63;
    switch (wi) {
      case 0:  src = wq + gn * 16384; scale = 0.125f; break;
      case 1:  src = wk + gn * 16384; scale = 1.0f;   break;
      case 2:  src = wv + gn * 16384; scale = 1.0f;   break;
      default: src = wo + gn * 16384; scale = 1.0f;   break;
    }
    dst = ws + OFF_WQ + wi * 1048576 + gn * 16384;
  }
  // --- phase 1: coalesced float4 reads -> packed bf16 pairs in LDS ---
#pragma unroll
  for (int i = 0; i < 16; ++i) {
    int flat = t + i * 256;          // float4 id, 0..4095
    int row = flat >> 8, col4 = flat & 255;
    float4 v = *(const float4*)(src + flat * 4);
    uint32_t lo = (uint32_t)(uint16_t)f2bf(v.x * scale) |
                  ((uint32_t)(uint16_t)f2bf(v.y * scale) << 16);
    uint32_t hi = (uint32_t)(uint16_t)f2bf(v.z * scale) |
                  ((uint32_t)(uint16_t)f2bf(v.w * scale) << 16);
    lt[row * 513 + col4 * 2]     = lo;
    lt[row * 513 + col4 * 2 + 1] = hi;
  }
  __syncthreads();
  // --- phase 2: swizzled LDS gather -> contiguous 16B global writes ---
#pragma unroll
  for (int i = 0; i < 8; ++i) {
    int s = t + i * 256;             // chunk-slot id, 0..2047
    int kb = s >> 6, l = s & 63, quad = l >> 4, cc = l & 15;
    int base = cc * 513 + kb * 16 + quad * 4;
    union { uint32_t u[4]; s16x8 v; } o;
    o.u[0] = lt[base];     o.u[1] = lt[base + 1];
    o.u[2] = lt[base + 2]; o.u[3] = lt[base + 3];
    *(s16x8*)(dst + s * 8) = o.v;
  }
}

// ---------------------------------------------------------------------------
// QKV projection R13: fused (N=3072) 128x384-tile -> 32x8 = 256 blocks =
// EXACTLY one full dispatch round (R12's 192-block grid left 25% of CUs
// idle). 8 waves (2M x 4N, per-wave 64m x 96n = acc[4][6]).
// Pipeline: ring of FOUR BK=32 half-buffers (32 chunks each: A 8 + B 24,
// 128 KiB total), staging lead = 3 halves (m201's depth): during half h we
// issue half h+3's 4 loads/wave ([A,B0] in phase0, [B1,B2] in phase1), and
// the end-of-half wait is the counted vmcnt(8) (12 outstanding -> oldest 4
// = half h+1 landed). Never drains to 0 until the tail (h>=29).
// Per half: 2 phases x 12 MFMA, setprio(1) around the MFMA cluster.
// Chunk-swizzled layout keeps every ds_read_b128 / async16 a conflict-free
// 1KB wave burst. nt in low block-index bits -> per-XCD B-panel affinity.
// Epilogue math byte-identical to R9-R12 (wsel per-fragment; 16-wide
// fragments never straddle the 1024-feature boundary).
// ---------------------------------------------------------------------------
__global__ __launch_bounds__(512, 2) void gemm_qkv8(short* __restrict__ ws) {
  __shared__ __align__(16) short LDS[65536];   // 4 ring slots x 32 chunks x 512
  int bid = blockIdx.x;             // 0..255
  int mt = bid >> 3, nt = bid & 7;  // nt low bits: same-XCD blocks share B panel
  const short* A  = ws + OFF_XB;    // [g 0..255][kb 0..31][64][8]
  const short* Bw = ws + OFF_WQ;    // fused: groups 0..191 (WQ|WK|WV contiguous)
  int t0 = threadIdx.x, lane = t0 & 63, wvi = t0 >> 6;
  int c = lane & 15, quad = lane >> 4;
  int wm = wvi >> 2, wn = wvi & 3;  // 2M x 4N waves; wave tile 64m x 96n
  f32x4 acc[4][6] = {};

  int gA  = mt * 8 + wvi;           // this wave's A staging row-group
  int gB0 = nt * 24 + wvi * 3;      // first of this wave's 3 B staging groups

  // ---- prologue: stage halves 0..2 (per-wave order per half: A,B0,B1,B2) ----
#pragma unroll
  for (int hs = 0; hs < 3; ++hs) {
    short* slot = &LDS[hs << 14];
    async16(&slot[wvi << 9],               A  + ((gA * 32 + hs) << 9) + lane * 8);
    async16(&slot[(8 + wvi * 3 + 0) << 9], Bw + (((gB0 + 0) * 32 + hs) << 9) + lane * 8);
    async16(&slot[(8 + wvi * 3 + 1) << 9], Bw + (((gB0 + 1) * 32 + hs) << 9) + lane * 8);
    async16(&slot[(8 + wvi * 3 + 2) << 9], Bw + (((gB0 + 2) * 32 + hs) << 9) + lane * 8);
  }
  asm volatile("s_waitcnt vmcnt(8)" ::: "memory");   // half 0 landed
  __builtin_amdgcn_s_barrier();

#pragma unroll 4
  for (int hh = 0; hh < 32; ++hh) {  // 32 halves of BK=32 (kb index == hh)
    short* slot = &LDS[(hh & 3) << 14];
    short* sst  = &LDS[((hh + 3) & 3) << 14];
    bool st = (hh < 29);
    int hs = hh + 3;
    // ---- phase 0: af[4] + bfr j0..2 || issue [A,B0] of half hh+3 ----
    bf16x8 af[4], bfr[3];
#pragma unroll
    for (int i = 0; i < 4; ++i)
      af[i] = *(const bf16x8*)&slot[((wm * 4 + i) << 9) + lane * 8];
#pragma unroll
    for (int j = 0; j < 3; ++j)
      bfr[j] = *(const bf16x8*)&slot[((8 + wn * 6 + j) << 9) + lane * 8];
    if (st) {
      async16(&sst[wvi << 9],               A  + ((gA * 32 + hs) << 9) + lane * 8);
      async16(&sst[(8 + wvi * 3 + 0) << 9], Bw + ((gB0 * 32 + hs) << 9) + lane * 8);
    }
    __builtin_amdgcn_s_barrier();
    asm volatile("s_waitcnt lgkmcnt(0)" ::: "memory");
    __builtin_amdgcn_sched_barrier(0);
    __builtin_amdgcn_s_setprio(1);
#pragma unroll
    for (int i = 0; i < 4; ++i)
#pragma unroll
      for (int j = 0; j < 3; ++j)
        acc[i][j] = __builtin_amdgcn_mfma_f32_16x16x32_bf16(af[i], bfr[j], acc[i][j], 0, 0, 0);
    __builtin_amdgcn_s_setprio(0);
    __builtin_amdgcn_s_barrier();
    // ---- phase 1: bfr j3..5 || issue [B1,B2] of half hh+3 ----
#pragma unroll
    for (int j = 0; j < 3; ++j)
      bfr[j] = *(const bf16x8*)&slot[((8 + wn * 6 + 3 + j) << 9) + lane * 8];
    if (st) {
      async16(&sst[(8 + wvi * 3 + 1) << 9], Bw + (((gB0 + 1) * 32 + hs) << 9) + lane * 8);
      async16(&sst[(8 + wvi * 3 + 2) << 9], Bw + (((gB0 + 2) * 32 + hs) << 9) + lane * 8);
    }
    __builtin_amdgcn_s_barrier();
    asm volatile("s_waitcnt lgkmcnt(0)" ::: "memory");
    __builtin_amdgcn_sched_barrier(0);
    __builtin_amdgcn_s_setprio(1);
#pragma unroll
    for (int i = 0; i < 4; ++i)
#pragma unroll
      for (int j = 0; j < 3; ++j)
        acc[i][3 + j] = __builtin_amdgcn_mfma_f32_16x16x32_bf16(af[i], bfr[j], acc[i][3 + j], 0, 0, 0);
    __builtin_amdgcn_s_setprio(0);
    // counted wait: outstanding = halves hh+1..min(hh+3,31); keep 2 halves
    // (8 loads) in flight; guarantee half hh+1 is in LDS for next iter.
    if (hh < 29)       asm volatile("s_waitcnt vmcnt(8)" ::: "memory");
    else if (hh == 29) asm volatile("s_waitcnt vmcnt(4)" ::: "memory");
    else               asm volatile("s_waitcnt vmcnt(0)" ::: "memory");
    __builtin_amdgcn_s_barrier();
  }

  // ---- epilogue: identical store math to R9-R12, 4x6 fragment grid ----
#pragma unroll
  for (int i = 0; i < 4; ++i) {
#pragma unroll
    for (int j = 0; j < 6; ++j) {
      int nf = nt * 384 + wn * 96 + j * 16 + c;   // fused feature 0..3071
      int wsel = nf >> 10;                        // 0=Q 1=K 2=V (frag never straddles)
      int n = nf & 1023;
      int h = n >> 6, d = n & 63;
      int mq = (mt << 7) + wm * 64 + i * 16 + quad * 4; // first of the 4 rows
      int bb = mq >> 9, srow = mq & 511;
      if (wsel < 2) {
        // Q_sw / K_sw: [bh][g][dblk][lane=qk*16+(row%16)][jd]; row%16=quad*4+r
        int dblk = d >> 5, qk = (d >> 3) & 3, jd = d & 7;
        int g = srow >> 4;
        short* outp = ws + (wsel == 0 ? OFF_Q : OFF_K);
        size_t base = (size_t)(bb * 16 + h) * 32768 +
                      (size_t)(((g * 2 + dblk) * 64 + qk * 16 + quad * 4)) * 8 + jd;
#pragma unroll
        for (int r = 0; r < 4; ++r) outp[base + r * 8] = f2bf(acc[i][j][r]);
      } else {
        // V_sw: [bh][dg][kblk][lane=qv*16+(d%16)][jv]; keys srow..srow+3
        int dg = d >> 4, cv = d & 15;
        int kblk = srow >> 5, qv = (srow >> 3) & 3, jv = srow & 7;
        s16x4 o;
#pragma unroll
        for (int r = 0; r < 4; ++r) o[r] = f2bf(acc[i][j][r]);
        *(s16x4*)&ws[OFF_VT + (size_t)(bb * 16 + h) * 32768 +
                     (size_t)((dg * 16 + kblk) * 64 + qv * 16 + cv) * 8 + jv] = o;
      }
    }
  }
}

// ---------------------------------------------------------------------------
// Attention v6 (R11): 128-key chunks — half the barrier/drain count.
// ---------------------------------------------------------------------------
__global__ __launch_bounds__(256, 2) void attn(short* __restrict__ ws) {
  __shared__ __align__(16) short Kb[8192];   // 16 chunks: [kgrel 0..7][dblk 0..1]
  __shared__ __align__(16) short Vb[8192];   // 16 chunks: [dg 0..3][kbrel 0..3]
  int bi = blockIdx.x;              // 0..511
  int bh = bi >> 2, qcr = bi & 3;
  int qc = (qcr + bh + 2 * (bh >> 6)) & 3;   // rotate so CU pairs mix light/heavy
  int t = threadIdx.x, lane = t & 63, wvi = t >> 6;
  int c = lane & 15, quad = lane >> 4;
  const short* Qsw  = ws + OFF_Q  + (size_t)bh * 32768;
  const short* Ksw  = ws + OFF_K  + (size_t)bh * 32768;
  const short* Vsw  = ws + OFF_VT + (size_t)bh * 32768;
  short* ct = ws + OFF_CT;
  int b = bh >> 4, h = bh & 15;

  int qt0 = qc * 128 + wvi * 32;    // two 16-row subtiles per wave
  int qt1 = qt0 + 16;
  int kn0 = (qt0 + 16 > NP) ? (qt0 + 16) : NP;
  int kn1 = (qt1 + 16 > NP) ? (qt1 + 16) : NP;
  int knb = (qc * 128 + 128 > NP) ? (qc * 128 + 128) : NP;
  int NCH = (knb + 127) >> 7;       // 128-key chunks staged by the block

  // Q^T B-frags from Q_sw (contiguous 1KB wave bursts)
  int qg0 = qt0 >> 4, qg1 = qt1 >> 4;
  bf16x8 q00 = *(const bf16x8*)(Qsw + ((qg0 * 2 + 0) * 64 + lane) * 8);
  bf16x8 q01 = *(const bf16x8*)(Qsw + ((qg0 * 2 + 1) * 64 + lane) * 8);
  bf16x8 q10 = *(const bf16x8*)(Qsw + ((qg1 * 2 + 0) * 64 + lane) * 8);
  bf16x8 q11 = *(const bf16x8*)(Qsw + ((qg1 * 2 + 1) * 64 + lane) * 8);

  f32x4 acc0[4] = {}, acc1[4] = {}; // ctx^T accumulators per subtile
  float l0 = 0.0f, l1 = 0.0f;       // in-lane softmax denominators
  int L0 = c + ((quad & 1) << 5);   // transpose source lane
  bool hilo = quad >= 2;

  for (int chn = 0; chn < NCH; ++chn) {
    int k0 = chn << 7;              // chunk covers keys k0 .. k0+127
    // --- stage 16 K-chunks + 16 V-chunks, 8 async16 per wave ---
    {
      int kg0 = k0 >> 4;            // first 16-key group
      int kblk0 = k0 >> 5;          // first 32-key block
#pragma unroll
      for (int i = 0; i < 4; ++i) {
        int ch = wvi * 4 + i;       // 0..15, wave-uniform
        int kgrel = ch >> 1, f = ch & 1;
        async16(&Kb[ch << 9], Ksw + (((kg0 + kgrel) * 2 + f) * 64 + lane) * 8);
        int dg = ch >> 2, kbrel = ch & 3;
        async16(&Vb[ch << 9], Vsw + ((dg * 16 + kblk0 + kbrel) * 64 + lane) * 8);
      }
    }
    __syncthreads();                // drains vmcnt for global_load_lds

#pragma unroll
    for (int hf = 0; hf < 2; ++hf) {
      int kh = k0 + (hf << 6);      // this 64-key half
      // K A-frags [m=key16][k=d] and V^T A-frags [m=d16][k=key32+..]
      bf16x8 ak[4][2], av[4][2];
#pragma unroll
      for (int mb = 0; mb < 4; ++mb)
#pragma unroll
        for (int f = 0; f < 2; ++f) {
          ak[mb][f] = *(const bf16x8*)&Kb[((((hf * 4 + mb) << 1) + f) << 9) + lane * 8];
          av[mb][f] = *(const bf16x8*)&Vb[(((mb << 2) + (hf << 1) + f) << 9) + lane * 8];
        }

#pragma unroll
      for (int s = 0; s < 2; ++s) {
        int qt = s ? qt1 : qt0;
        int kn = s ? kn1 : kn0;
        if (kh >= kn) continue;     // subtile finished for this half
        bf16x8 bq0 = s ? q10 : q00;
        bf16x8 bq1 = s ? q11 : q01;
        f32x4* acc = s ? acc1 : acc0;

        // --- S^T = K . Q^T : 4 m-blocks of 16 keys ---
        float p[4][4];
#pragma unroll
        for (int mb = 0; mb < 4; ++mb) {
          f32x4 st = {};
          st = __builtin_amdgcn_mfma_f32_16x16x32_bf16(ak[mb][0], bq0, st, 0, 0, 0);
          st = __builtin_amdgcn_mfma_f32_16x16x32_bf16(ak[mb][1], bq1, st, 0, 0, 0);
#pragma unroll
          for (int r = 0; r < 4; ++r) p[mb][r] = __expf(st[r]);
        }

        // --- prefix/causal mask (only halves that can contain invalid keys) ---
        if ((kh + 64 > NP) && (kh + 64 > qt + 1)) {
          int row = qt + c;
#pragma unroll
          for (int mb = 0; mb < 4; ++mb)
#pragma unroll
            for (int r = 0; r < 4; ++r) {
              int key = kh + mb * 16 + (quad << 2) + r;
              bool v = (row < NP) ? (key < NP) : (key <= row);
              p[mb][r] = v ? p[mb][r] : 0.0f;
            }
        }
        float ls = 0.0f;
#pragma unroll
        for (int mb = 0; mb < 4; ++mb)
#pragma unroll
          for (int r = 0; r < 4; ++r) ls += p[mb][r];
        if (s) l1 += ls; else l0 += ls;

        // --- per 32-key half: transpose to B-frag (R3-verified), then PV ---
#pragma unroll
        for (int hh = 0; hh < 2; ++hh) {
          float* pa = p[2 * hh];    // keys kh+32hh+{4quad'+r}
          float* pb = p[2 * hh + 1];
          uint32_t e0 = pack2bf(pa[0], pa[1]);
          uint32_t e1 = pack2bf(pa[2], pa[3]);
          uint32_t e2 = pack2bf(pb[0], pb[1]);
          uint32_t e3 = pack2bf(pb[2], pb[3]);
          uint32_t a0 = (uint32_t)__shfl((int)e0, L0);
          uint32_t b0 = (uint32_t)__shfl((int)e1, L0);
          uint32_t a1 = (uint32_t)__shfl((int)e0, L0 + 16);
          uint32_t b1 = (uint32_t)__shfl((int)e1, L0 + 16);
          uint32_t c0 = (uint32_t)__shfl((int)e2, L0);
          uint32_t d0 = (uint32_t)__shfl((int)e3, L0);
          uint32_t c1 = (uint32_t)__shfl((int)e2, L0 + 16);
          uint32_t d1 = (uint32_t)__shfl((int)e3, L0 + 16);
          union { uint32_t u[4]; bf16x8 v; } bp;
          bp.u[0] = hilo ? c0 : a0;
          bp.u[1] = hilo ? d0 : b0;
          bp.u[2] = hilo ? c1 : a1;
          bp.u[3] = hilo ? d1 : b1;
#pragma unroll
          for (int db = 0; db < 4; ++db)
            acc[db] = __builtin_amdgcn_mfma_f32_16x16x32_bf16(av[db][hh], bp.v, acc[db], 0, 0, 0);
        }
      }
    }
    __syncthreads();                // protect LDS before next stage
  }

  // --- finalize: quad-reduce l, normalize, store ctx SWIZZLED (CT_sw) ---
#pragma unroll
  for (int s = 0; s < 2; ++s) {
    float l = s ? l1 : l0;
    f32x4* acc = s ? acc1 : acc0;
    int qt = s ? qt1 : qt0;
    l += __shfl_xor(l, 16);
    l += __shfl_xor(l, 32);
    float inv = 1.0f / l;
    int g = (b * 512 + qt) >> 4;    // 16-row group (qt multiple of 16)
#pragma unroll
    for (int db = 0; db < 4; ++db) {
      int col0 = h * 64 + db * 16 + quad * 4;   // first of 4 cols (r-run)
      int kb = col0 >> 5, qp = (col0 & 31) >> 3, jo = col0 & 7;
      s16x4 o;
#pragma unroll
      for (int r = 0; r < 4; ++r) o[r] = f2bf(acc[db][r] * inv);
      *(s16x4*)&ct[(size_t)((g * 32 + kb) * 64 + qp * 16 + c) * 8 + jo] = o;
    }
  }
}

// ---------------------------------------------------------------------------
// Output projection (R9 structure, unchanged): 64m x 128n, BK=64, 512 blocks,
// swizzled 1KB-burst staging from CT_sw / WO_sw.
// ---------------------------------------------------------------------------
__global__ __launch_bounds__(256, 2) void gemm_out(const short* __restrict__ ws,
                                                   const float* __restrict__ bias,
                                                   float* __restrict__ out) {
  __shared__ __align__(16) short As[4096];   // 8 chunks
  __shared__ __align__(16) short Bs[8192];   // 16 chunks
  int bx = blockIdx.x;              // 0..511
  int mt = bx >> 3, nt = bx & 7;
  int m0 = mt << 6, n0 = nt << 7;
  const short* A  = ws + OFF_CT;
  const short* Bw = ws + OFF_WO;
  int t = threadIdx.x, lane = t & 63, wvi = t >> 6;
  int c = lane & 15, quad = lane >> 4;
  int wm = wvi >> 1, wn = wvi & 1;   // wave tile 32m x 64n
  int g0 = m0 >> 4, gn0 = n0 >> 4;
  f32x4 acc[2][4] = {};

  for (int kk = 0; kk < 1024; kk += 64) {
    int kb = kk >> 5;
#pragma unroll
    for (int i = 0; i < 6; ++i) {
      int ch = wvi * 6 + i;
      if (ch < 8) {
        int mg = ch >> 1, kh = ch & 1;
        async16(&As[ch << 9], A + ((g0 + mg) * 32 + kb + kh) * 512 + lane * 8);
      } else {
        int cb = ch - 8, mg = cb >> 1, kh = cb & 1;
        async16(&Bs[cb << 9], Bw + ((gn0 + mg) * 32 + kb + kh) * 512 + lane * 8);
      }
    }
    __syncthreads();                // drains vmcnt for global_load_lds

    bf16x8 af[2][2], bfr[4][2];
#pragma unroll
    for (int i = 0; i < 2; ++i)
#pragma unroll
      for (int kh = 0; kh < 2; ++kh)
        af[i][kh] = *(const bf16x8*)&As[((((wm * 2 + i) << 1) + kh) << 9) + lane * 8];
#pragma unroll
    for (int j = 0; j < 4; ++j)
#pragma unroll
      for (int kh = 0; kh < 2; ++kh)
        bfr[j][kh] = *(const bf16x8*)&Bs[((((wn * 4 + j) << 1) + kh) << 9) + lane * 8];
#pragma unroll
    for (int kh = 0; kh < 2; ++kh)
#pragma unroll
      for (int i = 0; i < 2; ++i)
#pragma unroll
        for (int j = 0; j < 4; ++j)
          acc[i][j] = __builtin_amdgcn_mfma_f32_16x16x32_bf16(af[i][kh], bfr[j][kh], acc[i][j], 0, 0, 0);
    __syncthreads();                // protect LDS before next stage
  }

#pragma unroll
  for (int j = 0; j < 4; ++j) {
    int n = n0 + wn * 64 + j * 16 + c;
    float bj = bias[n];
#pragma unroll
    for (int i = 0; i < 2; ++i) {
      int mq = m0 + wm * 32 + i * 16 + quad * 4;
#pragma unroll
      for (int r = 0; r < 4; ++r)
        out[(size_t)(mq + r) * 1024 + n] = acc[i][j][r] + bj;
    }
  }
}

extern "C" void kernel_launch(void* const* d_in, const int* in_sizes, int n_in,
                              void* d_out, int out_size, void* d_ws, size_t ws_size,
                              hipStream_t stream) {
  (void)in_sizes; (void)n_in; (void)out_size; (void)ws_size;  // needs 48 MB of d_ws
  const float* x  = (const float*)d_in[0];
  const float* wq = (const float*)d_in[1];
  const float* wk = (const float*)d_in[2];
  const float* wv = (const float*)d_in[3];
  const float* wo = (const float*)d_in[4];
  const float* bo = (const float*)d_in[5];
  short* ws = (short*)d_ws;
  float* out = (float*)d_out;

  cvt5<<<512, 256, 0, stream>>>(x, wq, wk, wv, wo, ws);
  gemm_qkv8<<<256, 512, 0, stream>>>(ws);
  attn<<<512, 256, 0, stream>>>(ws);
  gemm_out<<<512, 256, 0, stream>>>(ws, bo, out);
}

// Round 3
// 153.915 us; speedup vs baseline: 1.0318x; 1.0077x over previous
//
#include <hip/hip_runtime.h>
#include <stdint.h>
#include <math.h>

// Problem constants
#define NB_B 8
#define NB_S 512
#define NB_D 1024
#define NB_H 16
#define NB_HD 64
#define NP 196            // image patches: bidirectional prefix block
#define MTOT 4096         // B*S

// Workspace layout (offsets in bf16/short elements). Total 48 MB.
// ALL matrices that feed async16 staging (or wave-frag loads) are stored
// CHUNK-SWIZZLED: chunk (g = 16-row group, kb = 32-col block) = 512 shorts,
// [lane=quad*16+c][8 shorts], c = row%16, quad = (col%32)/8.
// => async16/frag reads are contiguous 1KB wave bursts (R9-verified win).
#define OFF_XB 0          // x bf16 swizzled:      [g 0..255][kb 0..31][64][8]
#define OFF_WQ 4194304    // w swizzled (each):    [gn 0..63][kb 0..31][64][8]
#define OFF_WK 5242880
#define OFF_WV 6291456
#define OFF_WO 7340032
#define OFF_Q  8388608    // Q swizzled: [bh][qg 0..31][dblk 0..1][64][8]
#define OFF_K  12582912   // K swizzled: [bh][kg 0..31][dblk 0..1][64][8]
#define OFF_VT 16777216   // V^T swizzled: [bh][dg 0..3][kblk 0..15][64][8]
#define OFF_CT 20971520   // ctx swizzled like XB: [g 0..255][kb 0..31][64][8]

typedef __attribute__((ext_vector_type(8))) short bf16x8;
typedef __attribute__((ext_vector_type(4))) float f32x4;
typedef __attribute__((ext_vector_type(4))) short s16x4;
typedef __attribute__((ext_vector_type(8))) short s16x8;

__device__ __forceinline__ short f2bf(float f) {
  union { float f; uint32_t u; } c; c.f = f;
  uint32_t r = (c.u + 0x7fffu + ((c.u >> 16) & 1u)) >> 16;   // RNE
  return (short)r;
}

// pack two fp32 -> one dword of two bf16 (round-half-up; softmax weights >=0)
__device__ __forceinline__ uint32_t pack2bf(float lo, float hi) {
  uint32_t ulo = __float_as_uint(lo) + 0x8000u;
  uint32_t uhi = __float_as_uint(hi) + 0x8000u;
  return __builtin_amdgcn_perm(uhi, ulo, 0x07060302u);  // [bf16(hi)|bf16(lo)]
}

__device__ __forceinline__ void async16(void* lds, const void* g) {
  // global -> LDS direct copy, 16B per lane; LDS dest = uniform base + lane*16
  __builtin_amdgcn_global_load_lds(
      (const __attribute__((address_space(1))) void*)g,
      (__attribute__((address_space(3))) void*)lds, 16, 0, 0);
}

// ---------------------------------------------------------------------------
// cvt5 v3: fp32 -> bf16 + chunk-swizzle via LDS transpose (R10-verified).
// ---------------------------------------------------------------------------
__global__ __launch_bounds__(256) void cvt5(const float* __restrict__ x,
                                            const float* __restrict__ wq,
                                            const float* __restrict__ wk,
                                            const float* __restrict__ wv,
                                            const float* __restrict__ wo,
                                            short* __restrict__ ws) {
  __shared__ uint32_t lt[16 * 513];   // 16 rows x 513 dwords (+pad: phase-2 conflict-free)
  int b = blockIdx.x, t = threadIdx.x;
  const float* src; short* dst; float scale;
  if (b < 256) {
    src = x + b * 16384;            // rows b*16 .. b*16+15
    dst = ws + OFF_XB + b * 16384;
    scale = 1.0f;
  } else {
    int wi = (b - 256) >> 6, gn = (b - 256) & 63;
    switch (wi) {
      case 0:  src = wq + gn * 16384; scale = 0.125f; break;
      case 1:  src = wk + gn * 16384; scale = 1.0f;   break;
      case 2:  src = wv + gn * 16384; scale = 1.0f;   break;
      default: src = wo + gn * 16384; scale = 1.0f;   break;
    }
    dst = ws + OFF_WQ + wi * 1048576 + gn * 16384;
  }
  // --- phase 1: coalesced float4 reads -> packed bf16 pairs in LDS ---
#pragma unroll
  for (int i = 0; i < 16; ++i) {
    int flat = t + i * 256;          // float4 id, 0..4095
    int row = flat >> 8, col4 = flat & 255;
    float4 v = *(const float4*)(src + flat * 4);
    uint32_t lo = (uint32_t)(uint16_t)f2bf(v.x * scale) |
                  ((uint32_t)(uint16_t)f2bf(v.y * scale) << 16);
    uint32_t hi = (uint32_t)(uint16_t)f2bf(v.z * scale) |
                  ((uint32_t)(uint16_t)f2bf(v.w * scale) << 16);
    lt[row * 513 + col4 * 2]     = lo;
    lt[row * 513 + col4 * 2 + 1] = hi;
  }
  __syncthreads();
  // --- phase 2: swizzled LDS gather -> contiguous 16B global writes ---
#pragma unroll
  for (int i = 0; i < 8; ++i) {
    int s = t + i * 256;             // chunk-slot id, 0..2047
    int kb = s >> 6, l = s & 63, quad = l >> 4, cc = l & 15;
    int base = cc * 513 + kb * 16 + quad * 4;
    union { uint32_t u[4]; s16x8 v; } o;
    o.u[0] = lt[base];     o.u[1] = lt[base + 1];
    o.u[2] = lt[base + 2]; o.u[3] = lt[base + 3];
    *(s16x8*)(dst + s * 8) = o.v;
  }
}

// ---------------------------------------------------------------------------
// QKV projection R14: revert to the R9/R10-verified 768-block, 128x128-tile,
// 4-wave, 2-blocks/CU structure (R12/R13 post-mortem: 1-block/CU deep
// pipelines lose the cross-block overlap that feeds the MFMA pipe during
// barrier drains). ONE minimal change vs R0: BK=32 -> BK=64 — stage two
// k-blocks per iteration using gemm_out's verified 2-kh chunk indexing.
// Halves the barrier-pair count (32->16) and doubles MFMA per drain
// (16->32/wave). LDS 16->32 KB/block; at 2 blocks/CU = 64 KB, occupancy
// unchanged. Epilogue byte-identical to R0.
// ---------------------------------------------------------------------------
__global__ __launch_bounds__(256, 2) void gemm_qkv(short* __restrict__ ws) {
  __shared__ __align__(16) short As[8192];   // 16 chunks: [mg 0..7][kh 0..1]
  __shared__ __align__(16) short Bs[8192];   // 16 chunks: [ng 0..7][kh 0..1]
  int bx = blockIdx.x;              // 0..767
  int wsel = bx >> 8;               // 0=Q 1=K 2=V
  int tile = bx & 255;
  int mt = tile >> 3, nt = tile & 7;
  int m0 = mt << 7, n0 = nt << 7;
  const short* A  = ws + OFF_XB;
  const short* Bw = ws + OFF_WQ + wsel * 1048576;
  int t = threadIdx.x, lane = t & 63, wvi = t >> 6;
  int c = lane & 15, quad = lane >> 4;
  int wm = wvi >> 1, wn = wvi & 1;
  int g0 = mt << 3, gn0 = nt << 3;  // 16-row group bases
  f32x4 acc[4][4] = {};

  for (int kk = 0; kk < 1024; kk += 64) {
    int kb = kk >> 5;               // even k-block index
#pragma unroll
    for (int i = 0; i < 4; ++i) {
      int ch = wvi * 4 + i;         // 0..15
      int mg = ch >> 1, kh = ch & 1;
      async16(&As[ch << 9], A  + ((g0  + mg) * 32 + kb + kh) * 512 + lane * 8);
      async16(&Bs[ch << 9], Bw + ((gn0 + mg) * 32 + kb + kh) * 512 + lane * 8);
    }
    __syncthreads();                // drains vmcnt for global_load_lds
    bf16x8 af[4][2], bfr[4][2];
#pragma unroll
    for (int i = 0; i < 4; ++i)
#pragma unroll
      for (int kh = 0; kh < 2; ++kh)
        af[i][kh]  = *(const bf16x8*)&As[((((wm * 4 + i) << 1) + kh) << 9) + lane * 8];
#pragma unroll
    for (int j = 0; j < 4; ++j)
#pragma unroll
      for (int kh = 0; kh < 2; ++kh)
        bfr[j][kh] = *(const bf16x8*)&Bs[((((wn * 4 + j) << 1) + kh) << 9) + lane * 8];
#pragma unroll
    for (int kh = 0; kh < 2; ++kh)
#pragma unroll
      for (int i = 0; i < 4; ++i)
#pragma unroll
        for (int j = 0; j < 4; ++j)
          acc[i][j] = __builtin_amdgcn_mfma_f32_16x16x32_bf16(af[i][kh], bfr[j][kh], acc[i][j], 0, 0, 0);
    __syncthreads();                // protect LDS before next stage
  }

#pragma unroll
  for (int i = 0; i < 4; ++i) {
#pragma unroll
    for (int j = 0; j < 4; ++j) {
      int n = n0 + wn * 64 + j * 16 + c;        // output feature
      int h = n >> 6, d = n & 63;
      int mq = m0 + wm * 64 + i * 16 + quad * 4; // first of the 4 rows (reg dim)
      int bb = mq >> 9, srow = mq & 511;
      if (wsel < 2) {
        // Q_sw / K_sw: [bh][g][dblk][lane=qk*16+(row%16)][jd]; row%16=quad*4+r
        int dblk = d >> 5, qk = (d >> 3) & 3, jd = d & 7;
        int g = srow >> 4;
        short* outp = ws + (wsel == 0 ? OFF_Q : OFF_K);
        size_t base = (size_t)(bb * 16 + h) * 32768 +
                      (size_t)(((g * 2 + dblk) * 64 + qk * 16 + quad * 4)) * 8 + jd;
#pragma unroll
        for (int r = 0; r < 4; ++r) outp[base + r * 8] = f2bf(acc[i][j][r]);
      } else {
        // V_sw: [bh][dg][kblk][lane=qv*16+(d%16)][jv]; keys srow..srow+3
        int dg = d >> 4, cv = d & 15;
        int kblk = srow >> 5, qv = (srow >> 3) & 3, jv = srow & 7;
        s16x4 o;
#pragma unroll
        for (int r = 0; r < 4; ++r) o[r] = f2bf(acc[i][j][r]);
        *(s16x4*)&ws[OFF_VT + (size_t)(bb * 16 + h) * 32768 +
                     (size_t)((dg * 16 + kblk) * 64 + qv * 16 + cv) * 8 + jv] = o;
      }
    }
  }
}

// ---------------------------------------------------------------------------
// Attention v6 (R11): 128-key chunks — half the barrier/drain count.
// ---------------------------------------------------------------------------
__global__ __launch_bounds__(256, 2) void attn(short* __restrict__ ws) {
  __shared__ __align__(16) short Kb[8192];   // 16 chunks: [kgrel 0..7][dblk 0..1]
  __shared__ __align__(16) short Vb[8192];   // 16 chunks: [dg 0..3][kbrel 0..3]
  int bi = blockIdx.x;              // 0..511
  int bh = bi >> 2, qcr = bi & 3;
  int qc = (qcr + bh + 2 * (bh >> 6)) & 3;   // rotate so CU pairs mix light/heavy
  int t = threadIdx.x, lane = t & 63, wvi = t >> 6;
  int c = lane & 15, quad = lane >> 4;
  const short* Qsw  = ws + OFF_Q  + (size_t)bh * 32768;
  const short* Ksw  = ws + OFF_K  + (size_t)bh * 32768;
  const short* Vsw  = ws + OFF_VT + (size_t)bh * 32768;
  short* ct = ws + OFF_CT;
  int b = bh >> 4, h = bh & 15;

  int qt0 = qc * 128 + wvi * 32;    // two 16-row subtiles per wave
  int qt1 = qt0 + 16;
  int kn0 = (qt0 + 16 > NP) ? (qt0 + 16) : NP;
  int kn1 = (qt1 + 16 > NP) ? (qt1 + 16) : NP;
  int knb = (qc * 128 + 128 > NP) ? (qc * 128 + 128) : NP;
  int NCH = (knb + 127) >> 7;       // 128-key chunks staged by the block

  // Q^T B-frags from Q_sw (contiguous 1KB wave bursts)
  int qg0 = qt0 >> 4, qg1 = qt1 >> 4;
  bf16x8 q00 = *(const bf16x8*)(Qsw + ((qg0 * 2 + 0) * 64 + lane) * 8);
  bf16x8 q01 = *(const bf16x8*)(Qsw + ((qg0 * 2 + 1) * 64 + lane) * 8);
  bf16x8 q10 = *(const bf16x8*)(Qsw + ((qg1 * 2 + 0) * 64 + lane) * 8);
  bf16x8 q11 = *(const bf16x8*)(Qsw + ((qg1 * 2 + 1) * 64 + lane) * 8);

  f32x4 acc0[4] = {}, acc1[4] = {}; // ctx^T accumulators per subtile
  float l0 = 0.0f, l1 = 0.0f;       // in-lane softmax denominators
  int L0 = c + ((quad & 1) << 5);   // transpose source lane
  bool hilo = quad >= 2;

  for (int chn = 0; chn < NCH; ++chn) {
    int k0 = chn << 7;              // chunk covers keys k0 .. k0+127
    // --- stage 16 K-chunks + 16 V-chunks, 8 async16 per wave ---
    {
      int kg0 = k0 >> 4;            // first 16-key group
      int kblk0 = k0 >> 5;          // first 32-key block
#pragma unroll
      for (int i = 0; i < 4; ++i) {
        int ch = wvi * 4 + i;       // 0..15, wave-uniform
        int kgrel = ch >> 1, f = ch & 1;
        async16(&Kb[ch << 9], Ksw + (((kg0 + kgrel) * 2 + f) * 64 + lane) * 8);
        int dg = ch >> 2, kbrel = ch & 3;
        async16(&Vb[ch << 9], Vsw + ((dg * 16 + kblk0 + kbrel) * 64 + lane) * 8);
      }
    }
    __syncthreads();                // drains vmcnt for global_load_lds

#pragma unroll
    for (int hf = 0; hf < 2; ++hf) {
      int kh = k0 + (hf << 6);      // this 64-key half
      // K A-frags [m=key16][k=d] and V^T A-frags [m=d16][k=key32+..]
      bf16x8 ak[4][2], av[4][2];
#pragma unroll
      for (int mb = 0; mb < 4; ++mb)
#pragma unroll
        for (int f = 0; f < 2; ++f) {
          ak[mb][f] = *(const bf16x8*)&Kb[((((hf * 4 + mb) << 1) + f) << 9) + lane * 8];
          av[mb][f] = *(const bf16x8*)&Vb[(((mb << 2) + (hf << 1) + f) << 9) + lane * 8];
        }

#pragma unroll
      for (int s = 0; s < 2; ++s) {
        int qt = s ? qt1 : qt0;
        int kn = s ? kn1 : kn0;
        if (kh >= kn) continue;     // subtile finished for this half
        bf16x8 bq0 = s ? q10 : q00;
        bf16x8 bq1 = s ? q11 : q01;
        f32x4* acc = s ? acc1 : acc0;

        // --- S^T = K . Q^T : 4 m-blocks of 16 keys ---
        float p[4][4];
#pragma unroll
        for (int mb = 0; mb < 4; ++mb) {
          f32x4 st = {};
          st = __builtin_amdgcn_mfma_f32_16x16x32_bf16(ak[mb][0], bq0, st, 0, 0, 0);
          st = __builtin_amdgcn_mfma_f32_16x16x32_bf16(ak[mb][1], bq1, st, 0, 0, 0);
#pragma unroll
          for (int r = 0; r < 4; ++r) p[mb][r] = __expf(st[r]);
        }

        // --- prefix/causal mask (only halves that can contain invalid keys) ---
        if ((kh + 64 > NP) && (kh + 64 > qt + 1)) {
          int row = qt + c;
#pragma unroll
          for (int mb = 0; mb < 4; ++mb)
#pragma unroll
            for (int r = 0; r < 4; ++r) {
              int key = kh + mb * 16 + (quad << 2) + r;
              bool v = (row < NP) ? (key < NP) : (key <= row);
              p[mb][r] = v ? p[mb][r] : 0.0f;
            }
        }
        float ls = 0.0f;
#pragma unroll
        for (int mb = 0; mb < 4; ++mb)
#pragma unroll
          for (int r = 0; r < 4; ++r) ls += p[mb][r];
        if (s) l1 += ls; else l0 += ls;

        // --- per 32-key half: transpose to B-frag (R3-verified), then PV ---
#pragma unroll
        for (int hh = 0; hh < 2; ++hh) {
          float* pa = p[2 * hh];    // keys kh+32hh+{4quad'+r}
          float* pb = p[2 * hh + 1];
          uint32_t e0 = pack2bf(pa[0], pa[1]);
          uint32_t e1 = pack2bf(pa[2], pa[3]);
          uint32_t e2 = pack2bf(pb[0], pb[1]);
          uint32_t e3 = pack2bf(pb[2], pb[3]);
          uint32_t a0 = (uint32_t)__shfl((int)e0, L0);
          uint32_t b0 = (uint32_t)__shfl((int)e1, L0);
          uint32_t a1 = (uint32_t)__shfl((int)e0, L0 + 16);
          uint32_t b1 = (uint32_t)__shfl((int)e1, L0 + 16);
          uint32_t c0 = (uint32_t)__shfl((int)e2, L0);
          uint32_t d0 = (uint32_t)__shfl((int)e3, L0);
          uint32_t c1 = (uint32_t)__shfl((int)e2, L0 + 16);
          uint32_t d1 = (uint32_t)__shfl((int)e3, L0 + 16);
          union { uint32_t u[4]; bf16x8 v; } bp;
          bp.u[0] = hilo ? c0 : a0;
          bp.u[1] = hilo ? d0 : b0;
          bp.u[2] = hilo ? c1 : a1;
          bp.u[3] = hilo ? d1 : b1;
#pragma unroll
          for (int db = 0; db < 4; ++db)
            acc[db] = __builtin_amdgcn_mfma_f32_16x16x32_bf16(av[db][hh], bp.v, acc[db], 0, 0, 0);
        }
      }
    }
    __syncthreads();                // protect LDS before next stage
  }

  // --- finalize: quad-reduce l, normalize, store ctx SWIZZLED (CT_sw) ---
#pragma unroll
  for (int s = 0; s < 2; ++s) {
    float l = s ? l1 : l0;
    f32x4* acc = s ? acc1 : acc0;
    int qt = s ? qt1 : qt0;
    l += __shfl_xor(l, 16);
    l += __shfl_xor(l, 32);
    float inv = 1.0f / l;
    int g = (b * 512 + qt) >> 4;    // 16-row group (qt multiple of 16)
#pragma unroll
    for (int db = 0; db < 4; ++db) {
      int col0 = h * 64 + db * 16 + quad * 4;   // first of 4 cols (r-run)
      int kb = col0 >> 5, qp = (col0 & 31) >> 3, jo = col0 & 7;
      s16x4 o;
#pragma unroll
      for (int r = 0; r < 4; ++r) o[r] = f2bf(acc[db][r] * inv);
      *(s16x4*)&ct[(size_t)((g * 32 + kb) * 64 + qp * 16 + c) * 8 + jo] = o;
    }
  }
}

// ---------------------------------------------------------------------------
// Output projection (R9 structure, unchanged): 64m x 128n, BK=64, 512 blocks,
// swizzled 1KB-burst staging from CT_sw / WO_sw.
// ---------------------------------------------------------------------------
__global__ __launch_bounds__(256, 2) void gemm_out(const short* __restrict__ ws,
                                                   const float* __restrict__ bias,
                                                   float* __restrict__ out) {
  __shared__ __align__(16) short As[4096];   // 8 chunks
  __shared__ __align__(16) short Bs[8192];   // 16 chunks
  int bx = blockIdx.x;              // 0..511
  int mt = bx >> 3, nt = bx & 7;
  int m0 = mt << 6, n0 = nt << 7;
  const short* A  = ws + OFF_CT;
  const short* Bw = ws + OFF_WO;
  int t = threadIdx.x, lane = t & 63, wvi = t >> 6;
  int c = lane & 15, quad = lane >> 4;
  int wm = wvi >> 1, wn = wvi & 1;   // wave tile 32m x 64n
  int g0 = m0 >> 4, gn0 = n0 >> 4;
  f32x4 acc[2][4] = {};

  for (int kk = 0; kk < 1024; kk += 64) {
    int kb = kk >> 5;
#pragma unroll
    for (int i = 0; i < 6; ++i) {
      int ch = wvi * 6 + i;
      if (ch < 8) {
        int mg = ch >> 1, kh = ch & 1;
        async16(&As[ch << 9], A + ((g0 + mg) * 32 + kb + kh) * 512 + lane * 8);
      } else {
        int cb = ch - 8, mg = cb >> 1, kh = cb & 1;
        async16(&Bs[cb << 9], Bw + ((gn0 + mg) * 32 + kb + kh) * 512 + lane * 8);
      }
    }
    __syncthreads();                // drains vmcnt for global_load_lds

    bf16x8 af[2][2], bfr[4][2];
#pragma unroll
    for (int i = 0; i < 2; ++i)
#pragma unroll
      for (int kh = 0; kh < 2; ++kh)
        af[i][kh] = *(const bf16x8*)&As[((((wm * 2 + i) << 1) + kh) << 9) + lane * 8];
#pragma unroll
    for (int j = 0; j < 4; ++j)
#pragma unroll
      for (int kh = 0; kh < 2; ++kh)
        bfr[j][kh] = *(const bf16x8*)&Bs[((((wn * 4 + j) << 1) + kh) << 9) + lane * 8];
#pragma unroll
    for (int kh = 0; kh < 2; ++kh)
#pragma unroll
      for (int i = 0; i < 2; ++i)
#pragma unroll
        for (int j = 0; j < 4; ++j)
          acc[i][j] = __builtin_amdgcn_mfma_f32_16x16x32_bf16(af[i][kh], bfr[j][kh], acc[i][j], 0, 0, 0);
    __syncthreads();                // protect LDS before next stage
  }

#pragma unroll
  for (int j = 0; j < 4; ++j) {
    int n = n0 + wn * 64 + j * 16 + c;
    float bj = bias[n];
#pragma unroll
    for (int i = 0; i < 2; ++i) {
      int mq = m0 + wm * 32 + i * 16 + quad * 4;
#pragma unroll
      for (int r = 0; r < 4; ++r)
        out[(size_t)(mq + r) * 1024 + n] = acc[i][j][r] + bj;
    }
  }
}

extern "C" void kernel_launch(void* const* d_in, const int* in_sizes, int n_in,
                              void* d_out, int out_size, void* d_ws, size_t ws_size,
                              hipStream_t stream) {
  (void)in_sizes; (void)n_in; (void)out_size; (void)ws_size;  // needs 48 MB of d_ws
  const float* x  = (const float*)d_in[0];
  const float* wq = (const float*)d_in[1];
  const float* wk = (const float*)d_in[2];
  const float* wv = (const float*)d_in[3];
  const float* wo = (const float*)d_in[4];
  const float* bo = (const float*)d_in[5];
  short* ws = (short*)d_ws;
  float* out = (float*)d_out;

  cvt5<<<512, 256, 0, stream>>>(x, wq, wk, wv, wo, ws);
  gemm_qkv<<<768, 256, 0, stream>>>(ws);
  attn<<<512, 256, 0, stream>>>(ws);
  gemm_out<<<512, 256, 0, stream>>>(ws, bo, out);
}

// Round 4
// 153.564 us; speedup vs baseline: 1.0341x; 1.0023x over previous
//
#include <hip/hip_runtime.h>
#include <stdint.h>
#include <math.h>

// Problem constants
#define NB_B 8
#define NB_S 512
#define NB_D 1024
#define NB_H 16
#define NB_HD 64
#define NP 196            // image patches: bidirectional prefix block
#define MTOT 4096         // B*S

// Workspace layout (offsets in bf16/short elements). Total 48 MB.
// ALL matrices that feed async16 staging (or wave-frag loads) are stored
// CHUNK-SWIZZLED: chunk (g = 16-row group, kb = 32-col block) = 512 shorts,
// [lane=quad*16+c][8 shorts], c = row%16, quad = (col%32)/8.
// => async16/frag reads are contiguous 1KB wave bursts (R9-verified win).
#define OFF_XB 0          // x bf16 swizzled:      [g 0..255][kb 0..31][64][8]
#define OFF_WQ 4194304    // w swizzled (each):    [gn 0..63][kb 0..31][64][8]
#define OFF_WK 5242880
#define OFF_WV 6291456
#define OFF_WO 7340032
#define OFF_Q  8388608    // Q swizzled: [bh][qg 0..31][dblk 0..1][64][8]
#define OFF_K  12582912   // K swizzled: [bh][kg 0..31][dblk 0..1][64][8]
#define OFF_VT 16777216   // V^T swizzled: [bh][dg 0..3][kblk 0..15][64][8]
#define OFF_CT 20971520   // ctx swizzled like XB: [g 0..255][kb 0..31][64][8]

typedef __attribute__((ext_vector_type(8))) short bf16x8;
typedef __attribute__((ext_vector_type(4))) float f32x4;
typedef __attribute__((ext_vector_type(4))) short s16x4;
typedef __attribute__((ext_vector_type(8))) short s16x8;

__device__ __forceinline__ short f2bf(float f) {
  union { float f; uint32_t u; } c; c.f = f;
  uint32_t r = (c.u + 0x7fffu + ((c.u >> 16) & 1u)) >> 16;   // RNE
  return (short)r;
}

// pack two fp32 -> one dword of two bf16 (round-half-up; softmax weights >=0)
__device__ __forceinline__ uint32_t pack2bf(float lo, float hi) {
  uint32_t ulo = __float_as_uint(lo) + 0x8000u;
  uint32_t uhi = __float_as_uint(hi) + 0x8000u;
  return __builtin_amdgcn_perm(uhi, ulo, 0x07060302u);  // [bf16(hi)|bf16(lo)]
}

__device__ __forceinline__ void async16(void* lds, const void* g) {
  // global -> LDS direct copy, 16B per lane; LDS dest = uniform base + lane*16
  __builtin_amdgcn_global_load_lds(
      (const __attribute__((address_space(1))) void*)g,
      (__attribute__((address_space(3))) void*)lds, 16, 0, 0);
}

// ---------------------------------------------------------------------------
// cvt5 v3: fp32 -> bf16 + chunk-swizzle via LDS transpose (R10-verified).
// ---------------------------------------------------------------------------
__global__ __launch_bounds__(256) void cvt5(const float* __restrict__ x,
                                            const float* __restrict__ wq,
                                            const float* __restrict__ wk,
                                            const float* __restrict__ wv,
                                            const float* __restrict__ wo,
                                            short* __restrict__ ws) {
  __shared__ uint32_t lt[16 * 513];   // 16 rows x 513 dwords (+pad: phase-2 conflict-free)
  int b = blockIdx.x, t = threadIdx.x;
  const float* src; short* dst; float scale;
  if (b < 256) {
    src = x + b * 16384;            // rows b*16 .. b*16+15
    dst = ws + OFF_XB + b * 16384;
    scale = 1.0f;
  } else {
    int wi = (b - 256) >> 6, gn = (b - 256) & 63;
    switch (wi) {
      case 0:  src = wq + gn * 16384; scale = 0.125f; break;
      case 1:  src = wk + gn * 16384; scale = 1.0f;   break;
      case 2:  src = wv + gn * 16384; scale = 1.0f;   break;
      default: src = wo + gn * 16384; scale = 1.0f;   break;
    }
    dst = ws + OFF_WQ + wi * 1048576 + gn * 16384;
  }
  // --- phase 1: coalesced float4 reads -> packed bf16 pairs in LDS ---
#pragma unroll
  for (int i = 0; i < 16; ++i) {
    int flat = t + i * 256;          // float4 id, 0..4095
    int row = flat >> 8, col4 = flat & 255;
    float4 v = *(const float4*)(src + flat * 4);
    uint32_t lo = (uint32_t)(uint16_t)f2bf(v.x * scale) |
                  ((uint32_t)(uint16_t)f2bf(v.y * scale) << 16);
    uint32_t hi = (uint32_t)(uint16_t)f2bf(v.z * scale) |
                  ((uint32_t)(uint16_t)f2bf(v.w * scale) << 16);
    lt[row * 513 + col4 * 2]     = lo;
    lt[row * 513 + col4 * 2 + 1] = hi;
  }
  __syncthreads();
  // --- phase 2: swizzled LDS gather -> contiguous 16B global writes ---
#pragma unroll
  for (int i = 0; i < 8; ++i) {
    int s = t + i * 256;             // chunk-slot id, 0..2047
    int kb = s >> 6, l = s & 63, quad = l >> 4, cc = l & 15;
    int base = cc * 513 + kb * 16 + quad * 4;
    union { uint32_t u[4]; s16x8 v; } o;
    o.u[0] = lt[base];     o.u[1] = lt[base + 1];
    o.u[2] = lt[base + 2]; o.u[3] = lt[base + 3];
    *(s16x8*)(dst + s * 8) = o.v;
  }
}

// ---------------------------------------------------------------------------
// QKV projection (R0-exact): 128x128 tile, BK=32, 768 blocks, swizzled
// 1KB-burst staging. R12/R13/R14 all lost to this structure — cross-block
// overlap at 2 blocks/CU beats intra-block pipelining here. Do not touch.
// ---------------------------------------------------------------------------
__global__ __launch_bounds__(256, 2) void gemm_qkv(short* __restrict__ ws) {
  __shared__ __align__(16) short As[4096];   // 8 chunks
  __shared__ __align__(16) short Bs[4096];
  int bx = blockIdx.x;              // 0..767
  int wsel = bx >> 8;               // 0=Q 1=K 2=V
  int tile = bx & 255;
  int mt = tile >> 3, nt = tile & 7;
  int m0 = mt << 7, n0 = nt << 7;
  const short* A  = ws + OFF_XB;
  const short* Bw = ws + OFF_WQ + wsel * 1048576;
  int t = threadIdx.x, lane = t & 63, wvi = t >> 6;
  int c = lane & 15, quad = lane >> 4;
  int wm = wvi >> 1, wn = wvi & 1;
  int g0 = mt << 3, gn0 = nt << 3;  // 16-row group bases
  f32x4 acc[4][4] = {};

  for (int kk = 0; kk < 1024; kk += 32) {
    int kb = kk >> 5;
#pragma unroll
    for (int i = 0; i < 2; ++i) {
      int ch = wvi * 2 + i;
      async16(&As[ch << 9], A  + ((g0  + ch) * 32 + kb) * 512 + lane * 8);
      async16(&Bs[ch << 9], Bw + ((gn0 + ch) * 32 + kb) * 512 + lane * 8);
    }
    __syncthreads();                // drains vmcnt for global_load_lds
    bf16x8 af[4], bfr[4];
#pragma unroll
    for (int i = 0; i < 4; ++i) af[i]  = *(const bf16x8*)&As[((wm * 4 + i) << 9) + lane * 8];
#pragma unroll
    for (int j = 0; j < 4; ++j) bfr[j] = *(const bf16x8*)&Bs[((wn * 4 + j) << 9) + lane * 8];
#pragma unroll
    for (int i = 0; i < 4; ++i)
#pragma unroll
      for (int j = 0; j < 4; ++j)
        acc[i][j] = __builtin_amdgcn_mfma_f32_16x16x32_bf16(af[i], bfr[j], acc[i][j], 0, 0, 0);
    __syncthreads();                // protect LDS before next stage
  }

#pragma unroll
  for (int i = 0; i < 4; ++i) {
#pragma unroll
    for (int j = 0; j < 4; ++j) {
      int n = n0 + wn * 64 + j * 16 + c;        // output feature
      int h = n >> 6, d = n & 63;
      int mq = m0 + wm * 64 + i * 16 + quad * 4; // first of the 4 rows (reg dim)
      int bb = mq >> 9, srow = mq & 511;
      if (wsel < 2) {
        // Q_sw / K_sw: [bh][g][dblk][lane=qk*16+(row%16)][jd]; row%16=quad*4+r
        int dblk = d >> 5, qk = (d >> 3) & 3, jd = d & 7;
        int g = srow >> 4;
        short* outp = ws + (wsel == 0 ? OFF_Q : OFF_K);
        size_t base = (size_t)(bb * 16 + h) * 32768 +
                      (size_t)(((g * 2 + dblk) * 64 + qk * 16 + quad * 4)) * 8 + jd;
#pragma unroll
        for (int r = 0; r < 4; ++r) outp[base + r * 8] = f2bf(acc[i][j][r]);
      } else {
        // V_sw: [bh][dg][kblk][lane=qv*16+(d%16)][jv]; keys srow..srow+3
        int dg = d >> 4, cv = d & 15;
        int kblk = srow >> 5, qv = (srow >> 3) & 3, jv = srow & 7;
        s16x4 o;
#pragma unroll
        for (int r = 0; r < 4; ++r) o[r] = f2bf(acc[i][j][r]);
        *(s16x4*)&ws[OFF_VT + (size_t)(bb * 16 + h) * 32768 +
                     (size_t)((dg * 16 + kblk) * 64 + qv * 16 + cv) * 8 + jv] = o;
      }
    }
  }
}

// ---------------------------------------------------------------------------
// Attention v7 (R15): NO LDS, NO BARRIERS. K/V are 8 MB total (L2/L3-fit);
// the chunk-swizzled layout makes direct global b128 frag loads perfectly
// coalesced 1KB wave bursts — staging through LDS was pure overhead
// (Common-mistake #7 / m169). Each wave now loops over ITS OWN key range
// (kn1), so the causal skip no longer forces wave lockstep. Offset algebra
// identical to the staged path (verified chunk-index correspondence):
//   Kb chunk (hf*4+mb)*2+f  == Ksw chunk ((kh>>4)+mb)*2+f
//   Vb chunk  mb*4+hf*2+f   == Vsw chunk  mb*16+(kh>>5)+f
// Compute/mask/transpose/store byte-identical to v6. LDS=0 -> ~3 blocks/CU.
// ---------------------------------------------------------------------------
__global__ __launch_bounds__(256) void attn(short* __restrict__ ws) {
  int bi = blockIdx.x;              // 0..511
  int bh = bi >> 2, qcr = bi & 3;
  int qc = (qcr + bh + 2 * (bh >> 6)) & 3;   // rotate so CU pairs mix light/heavy
  int t = threadIdx.x, lane = t & 63, wvi = t >> 6;
  int c = lane & 15, quad = lane >> 4;
  const short* Qsw  = ws + OFF_Q  + (size_t)bh * 32768;
  const short* Ksw  = ws + OFF_K  + (size_t)bh * 32768;
  const short* Vsw  = ws + OFF_VT + (size_t)bh * 32768;
  short* ct = ws + OFF_CT;
  int b = bh >> 4, h = bh & 15;

  int qt0 = qc * 128 + wvi * 32;    // two 16-row subtiles per wave
  int qt1 = qt0 + 16;
  int kn0 = (qt0 + 16 > NP) ? (qt0 + 16) : NP;
  int kn1 = (qt1 + 16 > NP) ? (qt1 + 16) : NP;   // kn1 >= kn0: wave's key bound

  // Q^T B-frags from Q_sw (contiguous 1KB wave bursts)
  int qg0 = qt0 >> 4, qg1 = qt1 >> 4;
  bf16x8 q00 = *(const bf16x8*)(Qsw + ((qg0 * 2 + 0) * 64 + lane) * 8);
  bf16x8 q01 = *(const bf16x8*)(Qsw + ((qg0 * 2 + 1) * 64 + lane) * 8);
  bf16x8 q10 = *(const bf16x8*)(Qsw + ((qg1 * 2 + 0) * 64 + lane) * 8);
  bf16x8 q11 = *(const bf16x8*)(Qsw + ((qg1 * 2 + 1) * 64 + lane) * 8);

  f32x4 acc0[4] = {}, acc1[4] = {}; // ctx^T accumulators per subtile
  float l0 = 0.0f, l1 = 0.0f;       // in-lane softmax denominators
  int L0 = c + ((quad & 1) << 5);   // transpose source lane
  bool hilo = quad >= 2;

  for (int kh = 0; kh < kn1; kh += 64) {   // per-wave 64-key steps
    // K A-frags [m=key16][k=d] and V^T A-frags [m=d16][k=key32+..],
    // loaded DIRECTLY from the swizzled global layout (1KB wave bursts).
    bf16x8 ak[4][2], av[4][2];
    int kg = kh >> 4, kblk = kh >> 5;
#pragma unroll
    for (int mb = 0; mb < 4; ++mb) {
      ak[mb][0] = *(const bf16x8*)(Ksw + (((kg + mb) * 2 + 0) * 64 + lane) * 8);
      ak[mb][1] = *(const bf16x8*)(Ksw + (((kg + mb) * 2 + 1) * 64 + lane) * 8);
      av[mb][0] = *(const bf16x8*)(Vsw + ((mb * 16 + kblk + 0) * 64 + lane) * 8);
      av[mb][1] = *(const bf16x8*)(Vsw + ((mb * 16 + kblk + 1) * 64 + lane) * 8);
    }

#pragma unroll
    for (int s = 0; s < 2; ++s) {
      int qt = s ? qt1 : qt0;
      int kn = s ? kn1 : kn0;
      if (kh >= kn) continue;       // subtile finished
      bf16x8 bq0 = s ? q10 : q00;
      bf16x8 bq1 = s ? q11 : q01;
      f32x4* acc = s ? acc1 : acc0;

      // --- S^T = K . Q^T : 4 m-blocks of 16 keys ---
      float p[4][4];
#pragma unroll
      for (int mb = 0; mb < 4; ++mb) {
        f32x4 st = {};
        st = __builtin_amdgcn_mfma_f32_16x16x32_bf16(ak[mb][0], bq0, st, 0, 0, 0);
        st = __builtin_amdgcn_mfma_f32_16x16x32_bf16(ak[mb][1], bq1, st, 0, 0, 0);
#pragma unroll
        for (int r = 0; r < 4; ++r) p[mb][r] = __expf(st[r]);
      }

      // --- prefix/causal mask (only halves that can contain invalid keys) ---
      if ((kh + 64 > NP) && (kh + 64 > qt + 1)) {
        int row = qt + c;
#pragma unroll
        for (int mb = 0; mb < 4; ++mb)
#pragma unroll
          for (int r = 0; r < 4; ++r) {
            int key = kh + mb * 16 + (quad << 2) + r;
            bool v = (row < NP) ? (key < NP) : (key <= row);
            p[mb][r] = v ? p[mb][r] : 0.0f;
          }
      }
      float ls = 0.0f;
#pragma unroll
      for (int mb = 0; mb < 4; ++mb)
#pragma unroll
        for (int r = 0; r < 4; ++r) ls += p[mb][r];
      if (s) l1 += ls; else l0 += ls;

      // --- per 32-key half: transpose to B-frag (R3-verified), then PV ---
#pragma unroll
      for (int hh = 0; hh < 2; ++hh) {
        float* pa = p[2 * hh];      // keys kh+32hh+{4quad'+r}
        float* pb = p[2 * hh + 1];
        uint32_t e0 = pack2bf(pa[0], pa[1]);
        uint32_t e1 = pack2bf(pa[2], pa[3]);
        uint32_t e2 = pack2bf(pb[0], pb[1]);
        uint32_t e3 = pack2bf(pb[2], pb[3]);
        uint32_t a0 = (uint32_t)__shfl((int)e0, L0);
        uint32_t b0 = (uint32_t)__shfl((int)e1, L0);
        uint32_t a1 = (uint32_t)__shfl((int)e0, L0 + 16);
        uint32_t b1 = (uint32_t)__shfl((int)e1, L0 + 16);
        uint32_t c0 = (uint32_t)__shfl((int)e2, L0);
        uint32_t d0 = (uint32_t)__shfl((int)e3, L0);
        uint32_t c1 = (uint32_t)__shfl((int)e2, L0 + 16);
        uint32_t d1 = (uint32_t)__shfl((int)e3, L0 + 16);
        union { uint32_t u[4]; bf16x8 v; } bp;
        bp.u[0] = hilo ? c0 : a0;
        bp.u[1] = hilo ? d0 : b0;
        bp.u[2] = hilo ? c1 : a1;
        bp.u[3] = hilo ? d1 : b1;
#pragma unroll
        for (int db = 0; db < 4; ++db)
          acc[db] = __builtin_amdgcn_mfma_f32_16x16x32_bf16(av[db][hh], bp.v, acc[db], 0, 0, 0);
      }
    }
  }

  // --- finalize: quad-reduce l, normalize, store ctx SWIZZLED (CT_sw) ---
#pragma unroll
  for (int s = 0; s < 2; ++s) {
    float l = s ? l1 : l0;
    f32x4* acc = s ? acc1 : acc0;
    int qt = s ? qt1 : qt0;
    l += __shfl_xor(l, 16);
    l += __shfl_xor(l, 32);
    float inv = 1.0f / l;
    int g = (b * 512 + qt) >> 4;    // 16-row group (qt multiple of 16)
#pragma unroll
    for (int db = 0; db < 4; ++db) {
      int col0 = h * 64 + db * 16 + quad * 4;   // first of 4 cols (r-run)
      int kb = col0 >> 5, qp = (col0 & 31) >> 3, jo = col0 & 7;
      s16x4 o;
#pragma unroll
      for (int r = 0; r < 4; ++r) o[r] = f2bf(acc[db][r] * inv);
      *(s16x4*)&ct[(size_t)((g * 32 + kb) * 64 + qp * 16 + c) * 8 + jo] = o;
    }
  }
}

// ---------------------------------------------------------------------------
// Output projection (R9 structure, unchanged): 64m x 128n, BK=64, 512 blocks,
// swizzled 1KB-burst staging from CT_sw / WO_sw.
// ---------------------------------------------------------------------------
__global__ __launch_bounds__(256, 2) void gemm_out(const short* __restrict__ ws,
                                                   const float* __restrict__ bias,
                                                   float* __restrict__ out) {
  __shared__ __align__(16) short As[4096];   // 8 chunks
  __shared__ __align__(16) short Bs[8192];   // 16 chunks
  int bx = blockIdx.x;              // 0..511
  int mt = bx >> 3, nt = bx & 7;
  int m0 = mt << 6, n0 = nt << 7;
  const short* A  = ws + OFF_CT;
  const short* Bw = ws + OFF_WO;
  int t = threadIdx.x, lane = t & 63, wvi = t >> 6;
  int c = lane & 15, quad = lane >> 4;
  int wm = wvi >> 1, wn = wvi & 1;   // wave tile 32m x 64n
  int g0 = m0 >> 4, gn0 = n0 >> 4;
  f32x4 acc[2][4] = {};

  for (int kk = 0; kk < 1024; kk += 64) {
    int kb = kk >> 5;
#pragma unroll
    for (int i = 0; i < 6; ++i) {
      int ch = wvi * 6 + i;
      if (ch < 8) {
        int mg = ch >> 1, kh = ch & 1;
        async16(&As[ch << 9], A + ((g0 + mg) * 32 + kb + kh) * 512 + lane * 8);
      } else {
        int cb = ch - 8, mg = cb >> 1, kh = cb & 1;
        async16(&Bs[cb << 9], Bw + ((gn0 + mg) * 32 + kb + kh) * 512 + lane * 8);
      }
    }
    __syncthreads();                // drains vmcnt for global_load_lds

    bf16x8 af[2][2], bfr[4][2];
#pragma unroll
    for (int i = 0; i < 2; ++i)
#pragma unroll
      for (int kh = 0; kh < 2; ++kh)
        af[i][kh] = *(const bf16x8*)&As[((((wm * 2 + i) << 1) + kh) << 9) + lane * 8];
#pragma unroll
    for (int j = 0; j < 4; ++j)
#pragma unroll
      for (int kh = 0; kh < 2; ++kh)
        bfr[j][kh] = *(const bf16x8*)&Bs[((((wn * 4 + j) << 1) + kh) << 9) + lane * 8];
#pragma unroll
    for (int kh = 0; kh < 2; ++kh)
#pragma unroll
      for (int i = 0; i < 2; ++i)
#pragma unroll
        for (int j = 0; j < 4; ++j)
          acc[i][j] = __builtin_amdgcn_mfma_f32_16x16x32_bf16(af[i][kh], bfr[j][kh], acc[i][j], 0, 0, 0);
    __syncthreads();                // protect LDS before next stage
  }

#pragma unroll
  for (int j = 0; j < 4; ++j) {
    int n = n0 + wn * 64 + j * 16 + c;
    float bj = bias[n];
#pragma unroll
    for (int i = 0; i < 2; ++i) {
      int mq = m0 + wm * 32 + i * 16 + quad * 4;
#pragma unroll
      for (int r = 0; r < 4; ++r)
        out[(size_t)(mq + r) * 1024 + n] = acc[i][j][r] + bj;
    }
  }
}

extern "C" void kernel_launch(void* const* d_in, const int* in_sizes, int n_in,
                              void* d_out, int out_size, void* d_ws, size_t ws_size,
                              hipStream_t stream) {
  (void)in_sizes; (void)n_in; (void)out_size; (void)ws_size;  // needs 48 MB of d_ws
  const float* x  = (const float*)d_in[0];
  const float* wq = (const float*)d_in[1];
  const float* wk = (const float*)d_in[2];
  const float* wv = (const float*)d_in[3];
  const float* wo = (const float*)d_in[4];
  const float* bo = (const float*)d_in[5];
  short* ws = (short*)d_ws;
  float* out = (float*)d_out;

  cvt5<<<512, 256, 0, stream>>>(x, wq, wk, wv, wo, ws);
  gemm_qkv<<<768, 256, 0, stream>>>(ws);
  attn<<<512, 256, 0, stream>>>(ws);
  gemm_out<<<512, 256, 0, stream>>>(ws, bo, out);
}